// Round 3
// baseline (457.048 us; speedup 1.0000x reference)
//
#include <hip/hip_runtime.h>
#include <hip/hip_bf16.h>

#define P_CLS 512
#define D_DIM 2048
#define CAP   32
#define TAU_INV 2.0f

// LDS swizzle: +1 float pad per 32 -> 2-way max bank aliasing (free, m136)
#define SW(a) ((a) + ((a) >> 5))

typedef short short8 __attribute__((ext_vector_type(8)));
typedef float f32x4 __attribute__((ext_vector_type(4)));

__device__ __forceinline__ unsigned short f2bf_bits(float x) {
  __hip_bfloat16 b = __float2bfloat16(x);
  unsigned short u;
  __builtin_memcpy(&u, &b, sizeof(u));
  return u;
}

__device__ __forceinline__ float xred_sum(float v) {
#pragma unroll
  for (int o = 1; o < 64; o <<= 1) v += __shfl_xor(v, o, 64);
  return v;
}
__device__ __forceinline__ float xred_max(float v) {
#pragma unroll
  for (int o = 1; o < 64; o <<= 1) v = fmaxf(v, __shfl_xor(v, o, 64));
  return v;
}

__global__ void k_init(int* cnt, float* accs, int* done) {
  int t = blockIdx.x * blockDim.x + threadIdx.x;
  if (t < P_CLS) cnt[t] = 0;
  if (t < 8) accs[t] = 0.f;
  if (t == 8) *done = 0;
}

__global__ void k_index(const int* __restrict__ label, int* __restrict__ cnt,
                        int* __restrict__ idx, int n) {
  int i = blockIdx.x * blockDim.x + threadIdx.x;
  if (i < n) {
    int p = label[i];
    int slot = atomicAdd(&cnt[p], 1);
    if (slot < CAP) idx[p * CAP + slot] = i;
  }
}

// R3: 1024-thread block (16 waves) per (class p, modality m). ONE row per
// wave: every wave issues its full 8 KB row burst at block start -> 128 KB
// of loads in flight per block immediately, no per-wave re-issue dependency
// chain (the flaw shared by all previous variants). Merge via LDS float
// atomics into a swizzled 8 KB accumulator (2-way bank aliasing = free).
// Two barriers total; wave 0 does the normalize + bf16 store epilogue.
__global__ __launch_bounds__(1024)
void k_centers(const float* __restrict__ f0, const float* __restrict__ f1,
               const float* __restrict__ f2, const int* __restrict__ cnt,
               const int* __restrict__ idx, __hip_bfloat16* __restrict__ cb,
               float* __restrict__ accs) {
  __shared__ float scen[D_DIM + D_DIM / 32];  // 8.25 KiB swizzled accumulator
  int p = blockIdx.x, m = blockIdx.y;
  const float* F = (m == 0) ? f0 : (m == 1) ? f1 : f2;
  int t = threadIdx.x, lane = t & 63, wv = t >> 6;
  int c = cnt[p];
  if (c > CAP) c = CAP;
  const int* idxp = idx + p * CAP;

  scen[t] = 0.f;
  scen[t + 1024] = 0.f;
  if (t < D_DIM / 32) scen[t + 2048] = 0.f;
  __syncthreads();

  // wave wv handles rows wv and wv+16 (test case: c == 16 -> one row/wave)
#pragma unroll
  for (int s = 0; s < 2; ++s) {
    int r = wv + 16 * s;
    if (r < c) {
      const f32x4* rp = (const f32x4*)(F + (long)idxp[r] * D_DIM) + lane;
      f32x4 buf[8];
#pragma unroll
      for (int j = 0; j < 8; ++j) buf[j] = rp[64 * j];
      float ssq = 0.f;
#pragma unroll
      for (int j = 0; j < 8; ++j) {
        f32x4 q = buf[j] * buf[j];
        ssq += q.x + q.y + q.z + q.w;
      }
      ssq = xred_sum(ssq);
      float w = 1.0f / fmaxf(sqrtf(ssq), 1e-12f);
#pragma unroll
      for (int j = 0; j < 8; ++j) {
        f32x4 v = buf[j] * w;
        int e = SW(4 * lane + 256 * j);  // 4*lane+k never crosses a 32-blk
        atomicAdd(&scen[e + 0], v.x);
        atomicAdd(&scen[e + 1], v.y);
        atomicAdd(&scen[e + 2], v.z);
        atomicAdd(&scen[e + 3], v.w);
      }
    }
  }
  __syncthreads();

  if (wv == 0) {
    f32x4 sv[8];
    float s2 = 0.f;
#pragma unroll
    for (int j = 0; j < 8; ++j) {
      int e = SW(4 * lane + 256 * j);
      sv[j].x = scen[e + 0];
      sv[j].y = scen[e + 1];
      sv[j].z = scen[e + 2];
      sv[j].w = scen[e + 3];
      f32x4 q = sv[j] * sv[j];
      s2 += q.x + q.y + q.z + q.w;
    }
    s2 = xred_sum(s2);
    float sn = sqrtf(s2);
    float inv = 1.0f / fmaxf(sn, 1e-12f);
    __hip_bfloat16* dst = cb + ((long)m * P_CLS + p) * D_DIM;
#pragma unroll
    for (int j = 0; j < 8; ++j) {
      f32x4 o = sv[j] * inv;
      ushort4 h;
      h.x = f2bf_bits(o.x); h.y = f2bf_bits(o.y);
      h.z = f2bf_bits(o.z); h.w = f2bf_bits(o.w);
      ((ushort4*)dst)[lane + 64 * j] = h;
    }
    if (lane == 0 && c > 0) atomicAdd(&accs[0], sn);
  }
}

// Split-K bf16 MFMA GEMM (gridDim.z slices), 64x64 tiles, LDS double-buffer
// + depth-2 reg prefetch, one barrier per K-step.
__global__ __launch_bounds__(256)
void k_gemm(const __hip_bfloat16* __restrict__ cbh, float* __restrict__ logits) {
  __shared__ __align__(16) unsigned short As[2][64 * 40], Bs[2][64 * 40];
  int pair = blockIdx.y, kz = blockIdx.z, nkz = gridDim.z;
  int ksl = D_DIM / nkz;
  int ma = (pair == 2) ? 1 : 0;
  int mb = (pair == 0) ? 1 : 2;
  const unsigned short* A =
      (const unsigned short*)cbh + (long)ma * P_CLS * D_DIM + kz * ksl;
  const unsigned short* B =
      (const unsigned short*)cbh + (long)mb * P_CLS * D_DIM + kz * ksl;
  float* C = logits + ((long)kz * 3 + pair) * P_CLS * P_CLS;
  int tm = (blockIdx.x >> 3) * 64, tn = (blockIdx.x & 7) * 64;
  int t = threadIdx.x, lane = t & 63, wv = t >> 6;
  int srow = t >> 2, skc = (t & 3) * 8;
  int quad = lane >> 4, mr = lane & 15;
  const unsigned short* pa = A + (long)(tm + srow) * D_DIM + skc;
  const unsigned short* pb = B + (long)(tn + srow) * D_DIM + skc;
  f32x4 acc[4] = {{0,0,0,0},{0,0,0,0},{0,0,0,0},{0,0,0,0}};
  uint4 av = *(const uint4*)pa, bv = *(const uint4*)pb;
  *(uint4*)(&As[0][srow * 40 + skc]) = av;
  *(uint4*)(&Bs[0][srow * 40 + skc]) = bv;
  av = *(const uint4*)(pa + 32); bv = *(const uint4*)(pb + 32);
  const int NIT = ksl / 32;
  for (int it = 0; it < NIT; ++it) {
    __syncthreads();
    int cur = it & 1;
    if (it + 1 < NIT) {
      *(uint4*)(&As[cur ^ 1][srow * 40 + skc]) = av;
      *(uint4*)(&Bs[cur ^ 1][srow * 40 + skc]) = bv;
    }
    if (it + 2 < NIT) {
      av = *(const uint4*)(pa + (it + 2) * 32);
      bv = *(const uint4*)(pb + (it + 2) * 32);
    }
    short8 af = *(const short8*)(&As[cur][(wv * 16 + mr) * 40 + quad * 8]);
#pragma unroll
    for (int nb = 0; nb < 4; ++nb) {
      short8 bfr = *(const short8*)(&Bs[cur][(nb * 16 + mr) * 40 + quad * 8]);
      acc[nb] = __builtin_amdgcn_mfma_f32_16x16x32_bf16(af, bfr, acc[nb], 0, 0, 0);
    }
  }
  int crow = tm + wv * 16 + quad * 4;
#pragma unroll
  for (int nb = 0; nb < 4; ++nb)
#pragma unroll
    for (int r = 0; r < 4; ++r)
      C[(long)(crow + r) * P_CLS + tn + nb * 16 + mr] = acc[nb][r] * TAU_INV;
}

// One block per (pair,p) row: sum nkz split-K partials, logsumexp - diag.
// Last finishing block (atomic ticket) computes the final scalar output.
__global__ __launch_bounds__(256)
void k_lse(const float* __restrict__ logits, float* __restrict__ accs, int nkz,
           int* __restrict__ done, float* __restrict__ out, float invN) {
  __shared__ float sred[8];
  int row = blockIdx.x;  // 0 .. 3*P-1
  int p = row & (P_CLS - 1);
  int t = threadIdx.x, lane = t & 63, wv = t >> 6;
  float v0 = 0.f, v1 = 0.f, diag = 0.f;
  for (int z = 0; z < nkz; ++z) {
    const float* L = logits + ((long)z * 3 * P_CLS + row) * P_CLS;
    v0 += L[t];
    v1 += L[t + 256];
  }
  float mx = xred_max(fmaxf(v0, v1));
  if (lane == 0) sred[wv] = mx;
  __syncthreads();
  mx = fmaxf(fmaxf(sred[0], sred[1]), fmaxf(sred[2], sred[3]));
  float e = expf(v0 - mx) + expf(v1 - mx);
  e = xred_sum(e);
  if (lane == 0) sred[4 + wv] = e;
  __syncthreads();
  if (t == 0) {
    float tot = sred[4] + sred[5] + sred[6] + sred[7];
    for (int z = 0; z < nkz; ++z)
      diag += logits[((long)z * 3 * P_CLS + row) * P_CLS + p];
    atomicAdd(&accs[1], mx + logf(tot) - diag);
    __threadfence();
    int prev = atomicAdd(done, 1);
    if (prev == 3 * P_CLS - 1) {
      // read via device-scope atomics to cross XCD L2s
      float a0 = atomicAdd(&accs[0], 0.f);
      float a1 = atomicAdd(&accs[1], 0.f);
      out[0] = 6.0f - 2.0f * invN * a0 + a1 * (1.0f / (float)P_CLS);
    }
  }
}

extern "C" void kernel_launch(void* const* d_in, const int* in_sizes, int n_in,
                              void* d_out, int out_size, void* d_ws, size_t ws_size,
                              hipStream_t stream) {
  const float* fvp = (const float*)d_in[0];
  const float* fap = (const float*)d_in[1];
  const float* frp = (const float*)d_in[2];
  const int* label = (const int*)d_in[3];
  int N = in_sizes[3];

  char* ws = (char*)d_ws;
  int* cnt = (int*)ws;                                    // 2 KiB
  int* idx = (int*)(ws + 2048);                           // 64 KiB
  float* accs = (float*)(ws + 2048 + 65536);              // 32 B
  int* done = (int*)(ws + 2048 + 65536 + 32);             // 4 B
  __hip_bfloat16* cb = (__hip_bfloat16*)(ws + 131072);    // 6 MiB
  float* logits = (float*)(ws + 131072 + 3ul * P_CLS * D_DIM * 2);

  size_t base = 131072 + 3ul * P_CLS * D_DIM * 2;
  size_t per_z = 3ul * P_CLS * P_CLS * 4;
  int KZ = (ws_size >= base + 4 * per_z) ? 4 : 2;

  hipLaunchKernelGGL(k_init, dim3(1), dim3(512), 0, stream, cnt, accs, done);
  hipLaunchKernelGGL(k_index, dim3((N + 255) / 256), dim3(256), 0, stream,
                     label, cnt, idx, N);
  hipLaunchKernelGGL(k_centers, dim3(P_CLS, 3), dim3(1024), 0, stream,
                     fvp, fap, frp, cnt, idx, cb, accs);
  hipLaunchKernelGGL(k_gemm, dim3(64, 3, KZ), dim3(256), 0, stream, cb, logits);
  hipLaunchKernelGGL(k_lse, dim3(3 * P_CLS), dim3(256), 0, stream, logits, accs,
                     KZ, done, (float*)d_out, 1.0f / (float)N);
}

// Round 4
// 259.868 us; speedup vs baseline: 1.7588x; 1.7588x over previous
//
#include <hip/hip_runtime.h>
#include <hip/hip_bf16.h>

#define P_CLS 512
#define D_DIM 2048
#define CAP   32
#define TAU_INV 2.0f

typedef short short8 __attribute__((ext_vector_type(8)));
typedef float f32x4 __attribute__((ext_vector_type(4)));

__device__ __forceinline__ unsigned short f2bf_bits(float x) {
  __hip_bfloat16 b = __float2bfloat16(x);
  unsigned short u;
  __builtin_memcpy(&u, &b, sizeof(u));
  return u;
}

__device__ __forceinline__ float xred_sum(float v) {
#pragma unroll
  for (int o = 1; o < 64; o <<= 1) v += __shfl_xor(v, o, 64);
  return v;
}
__device__ __forceinline__ float xred_max(float v) {
#pragma unroll
  for (int o = 1; o < 64; o <<= 1) v = fmaxf(v, __shfl_xor(v, o, 64));
  return v;
}

__global__ void k_init(int* cnt, float* accs, int* done) {
  int t = blockIdx.x * blockDim.x + threadIdx.x;
  if (t < P_CLS) cnt[t] = 0;
  if (t < 8) accs[t] = 0.f;
  if (t == 8) *done = 0;
}

__global__ void k_index(const int* __restrict__ label, int* __restrict__ cnt,
                        int* __restrict__ idx, int n) {
  int i = blockIdx.x * blockDim.x + threadIdx.x;
  if (i < n) {
    int p = label[i];
    int slot = atomicAdd(&cnt[p], 1);
    if (slot < CAP) idx[p * CAP + slot] = i;
  }
}

// R4: 256-thread block per (class p, modality m), COLUMN-sliced: wave wv owns
// columns [wv*512, wv*512+512) of ALL 16 rows. Per lane: 32 independent f32x4
// loads (128 VGPRs of buffer) issued as ONE burst; the empty asm with a
// memory clobber forbids the compiler from sinking loads below it (the R2
// failure). Row norms: per-wave partial ssq + shfl reduce -> 64-float LDS
// exchange -> one barrier -> weights broadcast -> FMA accumulate. Waves own
// disjoint columns so no cross-wave merge of the center; 2 barriers total.
__global__ __launch_bounds__(256)
void k_centers(const float* __restrict__ f0, const float* __restrict__ f1,
               const float* __restrict__ f2, const int* __restrict__ cnt,
               const int* __restrict__ idx, __hip_bfloat16* __restrict__ cb,
               float* __restrict__ accs) {
  __shared__ float ssqp[64];
  __shared__ float scr[4];
  int p = blockIdx.x, m = blockIdx.y;
  const float* F = (m == 0) ? f0 : (m == 1) ? f1 : f2;
  int t = threadIdx.x, lane = t & 63, wv = t >> 6;
  int c = cnt[p];
  if (c > CAP) c = CAP;
  const int* idxp = idx + p * CAP;
  const int4* ip4 = (const int4*)idxp;
  int4 iv0 = ip4[0], iv1 = ip4[1], iv2 = ip4[2], iv3 = ip4[3];
  int rr[16] = {iv0.x, iv0.y, iv0.z, iv0.w, iv1.x, iv1.y, iv1.z, iv1.w,
                iv2.x, iv2.y, iv2.z, iv2.w, iv3.x, iv3.y, iv3.z, iv3.w};

  int vidx = wv * 128 + lane;  // f32x4 index of this lane's first column slot
  f32x4 bufa[16], bufb[16];
#pragma unroll
  for (int r = 0; r < 16; ++r) {
    long rc = (r < c) ? rr[r] : 0;  // clamp invalid slots to a safe row
    const f32x4* rp = (const f32x4*)(F + rc * D_DIM) + vidx;
    bufa[r] = rp[0];
    bufb[r] = rp[64];
  }
  asm volatile("" ::: "memory");  // pin the whole 32-load burst above compute

#pragma unroll
  for (int r = 0; r < 16; ++r) {
    f32x4 qa = bufa[r] * bufa[r], qb = bufb[r] * bufb[r];
    float s = qa.x + qa.y + qa.z + qa.w + qb.x + qb.y + qb.z + qb.w;
    s = xred_sum(s);
    if (lane == 0) ssqp[r * 4 + wv] = s;
  }
  __syncthreads();
  f32x4 acc0 = {0, 0, 0, 0}, acc1 = {0, 0, 0, 0};
#pragma unroll
  for (int r = 0; r < 16; ++r) {
    float ss = ssqp[r * 4 + 0] + ssqp[r * 4 + 1] + ssqp[r * 4 + 2] + ssqp[r * 4 + 3];
    float wr = (r < c) ? (1.0f / fmaxf(sqrtf(ss), 1e-12f)) : 0.f;
    acc0 += bufa[r] * wr;
    acc1 += bufb[r] * wr;
  }

  if (c > 16) {  // general path (uniform branch; unused when c <= 16)
    const int4* ip4b = ip4 + 4;
    int4 jv0 = ip4b[0], jv1 = ip4b[1], jv2 = ip4b[2], jv3 = ip4b[3];
    int rr2[16] = {jv0.x, jv0.y, jv0.z, jv0.w, jv1.x, jv1.y, jv1.z, jv1.w,
                   jv2.x, jv2.y, jv2.z, jv2.w, jv3.x, jv3.y, jv3.z, jv3.w};
    __syncthreads();  // all waves past ssqp reads before reuse
#pragma unroll
    for (int r = 0; r < 16; ++r) {
      long rc = (16 + r < c) ? rr2[r] : 0;
      const f32x4* rp = (const f32x4*)(F + rc * D_DIM) + vidx;
      bufa[r] = rp[0];
      bufb[r] = rp[64];
    }
    asm volatile("" ::: "memory");
#pragma unroll
    for (int r = 0; r < 16; ++r) {
      f32x4 qa = bufa[r] * bufa[r], qb = bufb[r] * bufb[r];
      float s = qa.x + qa.y + qa.z + qa.w + qb.x + qb.y + qb.z + qb.w;
      s = xred_sum(s);
      if (lane == 0) ssqp[r * 4 + wv] = s;
    }
    __syncthreads();
#pragma unroll
    for (int r = 0; r < 16; ++r) {
      float ss = ssqp[r * 4 + 0] + ssqp[r * 4 + 1] + ssqp[r * 4 + 2] + ssqp[r * 4 + 3];
      float wr = (16 + r < c) ? (1.0f / fmaxf(sqrtf(ss), 1e-12f)) : 0.f;
      acc0 += bufa[r] * wr;
      acc1 += bufb[r] * wr;
    }
  }

  // center norm across the block's disjoint column slices
  f32x4 qa = acc0 * acc0, qb = acc1 * acc1;
  float s2 = qa.x + qa.y + qa.z + qa.w + qb.x + qb.y + qb.z + qb.w;
  s2 = xred_sum(s2);
  if (lane == 0) scr[wv] = s2;
  __syncthreads();
  s2 = scr[0] + scr[1] + scr[2] + scr[3];
  float sn = sqrtf(s2);
  float inv = 1.0f / fmaxf(sn, 1e-12f);
  __hip_bfloat16* dst = cb + ((long)m * P_CLS + p) * D_DIM;
  f32x4 o0 = acc0 * inv, o1 = acc1 * inv;
  ushort4 h0, h1;
  h0.x = f2bf_bits(o0.x); h0.y = f2bf_bits(o0.y);
  h0.z = f2bf_bits(o0.z); h0.w = f2bf_bits(o0.w);
  h1.x = f2bf_bits(o1.x); h1.y = f2bf_bits(o1.y);
  h1.z = f2bf_bits(o1.z); h1.w = f2bf_bits(o1.w);
  ((ushort4*)dst)[vidx] = h0;
  ((ushort4*)dst)[vidx + 64] = h1;
  if (t == 0 && c > 0) atomicAdd(&accs[0], sn);
}

// Split-K bf16 MFMA GEMM (gridDim.z slices), 64x64 tiles, LDS double-buffer
// + depth-2 reg prefetch, one barrier per K-step.
__global__ __launch_bounds__(256)
void k_gemm(const __hip_bfloat16* __restrict__ cbh, float* __restrict__ logits) {
  __shared__ __align__(16) unsigned short As[2][64 * 40], Bs[2][64 * 40];
  int pair = blockIdx.y, kz = blockIdx.z, nkz = gridDim.z;
  int ksl = D_DIM / nkz;
  int ma = (pair == 2) ? 1 : 0;
  int mb = (pair == 0) ? 1 : 2;
  const unsigned short* A =
      (const unsigned short*)cbh + (long)ma * P_CLS * D_DIM + kz * ksl;
  const unsigned short* B =
      (const unsigned short*)cbh + (long)mb * P_CLS * D_DIM + kz * ksl;
  float* C = logits + ((long)kz * 3 + pair) * P_CLS * P_CLS;
  int tm = (blockIdx.x >> 3) * 64, tn = (blockIdx.x & 7) * 64;
  int t = threadIdx.x, lane = t & 63, wv = t >> 6;
  int srow = t >> 2, skc = (t & 3) * 8;
  int quad = lane >> 4, mr = lane & 15;
  const unsigned short* pa = A + (long)(tm + srow) * D_DIM + skc;
  const unsigned short* pb = B + (long)(tn + srow) * D_DIM + skc;
  f32x4 acc[4] = {{0,0,0,0},{0,0,0,0},{0,0,0,0},{0,0,0,0}};
  uint4 av = *(const uint4*)pa, bv = *(const uint4*)pb;
  *(uint4*)(&As[0][srow * 40 + skc]) = av;
  *(uint4*)(&Bs[0][srow * 40 + skc]) = bv;
  av = *(const uint4*)(pa + 32); bv = *(const uint4*)(pb + 32);
  const int NIT = ksl / 32;
  for (int it = 0; it < NIT; ++it) {
    __syncthreads();
    int cur = it & 1;
    if (it + 1 < NIT) {
      *(uint4*)(&As[cur ^ 1][srow * 40 + skc]) = av;
      *(uint4*)(&Bs[cur ^ 1][srow * 40 + skc]) = bv;
    }
    if (it + 2 < NIT) {
      av = *(const uint4*)(pa + (it + 2) * 32);
      bv = *(const uint4*)(pb + (it + 2) * 32);
    }
    short8 af = *(const short8*)(&As[cur][(wv * 16 + mr) * 40 + quad * 8]);
#pragma unroll
    for (int nb = 0; nb < 4; ++nb) {
      short8 bfr = *(const short8*)(&Bs[cur][(nb * 16 + mr) * 40 + quad * 8]);
      acc[nb] = __builtin_amdgcn_mfma_f32_16x16x32_bf16(af, bfr, acc[nb], 0, 0, 0);
    }
  }
  int crow = tm + wv * 16 + quad * 4;
#pragma unroll
  for (int nb = 0; nb < 4; ++nb)
#pragma unroll
    for (int r = 0; r < 4; ++r)
      C[(long)(crow + r) * P_CLS + tn + nb * 16 + mr] = acc[nb][r] * TAU_INV;
}

// One block per (pair,p) row: sum nkz split-K partials, logsumexp - diag.
// Last finishing block (atomic ticket) computes the final scalar output.
__global__ __launch_bounds__(256)
void k_lse(const float* __restrict__ logits, float* __restrict__ accs, int nkz,
           int* __restrict__ done, float* __restrict__ out, float invN) {
  __shared__ float sred[8];
  int row = blockIdx.x;  // 0 .. 3*P-1
  int p = row & (P_CLS - 1);
  int t = threadIdx.x, lane = t & 63, wv = t >> 6;
  float v0 = 0.f, v1 = 0.f, diag = 0.f;
  for (int z = 0; z < nkz; ++z) {
    const float* L = logits + ((long)z * 3 * P_CLS + row) * P_CLS;
    v0 += L[t];
    v1 += L[t + 256];
  }
  float mx = xred_max(fmaxf(v0, v1));
  if (lane == 0) sred[wv] = mx;
  __syncthreads();
  mx = fmaxf(fmaxf(sred[0], sred[1]), fmaxf(sred[2], sred[3]));
  float e = expf(v0 - mx) + expf(v1 - mx);
  e = xred_sum(e);
  if (lane == 0) sred[4 + wv] = e;
  __syncthreads();
  if (t == 0) {
    float tot = sred[4] + sred[5] + sred[6] + sred[7];
    for (int z = 0; z < nkz; ++z)
      diag += logits[((long)z * 3 * P_CLS + row) * P_CLS + p];
    atomicAdd(&accs[1], mx + logf(tot) - diag);
    __threadfence();
    int prev = atomicAdd(done, 1);
    if (prev == 3 * P_CLS - 1) {
      float a0 = atomicAdd(&accs[0], 0.f);
      float a1 = atomicAdd(&accs[1], 0.f);
      out[0] = 6.0f - 2.0f * invN * a0 + a1 * (1.0f / (float)P_CLS);
    }
  }
}

extern "C" void kernel_launch(void* const* d_in, const int* in_sizes, int n_in,
                              void* d_out, int out_size, void* d_ws, size_t ws_size,
                              hipStream_t stream) {
  const float* fvp = (const float*)d_in[0];
  const float* fap = (const float*)d_in[1];
  const float* frp = (const float*)d_in[2];
  const int* label = (const int*)d_in[3];
  int N = in_sizes[3];

  char* ws = (char*)d_ws;
  int* cnt = (int*)ws;                                    // 2 KiB
  int* idx = (int*)(ws + 2048);                           // 64 KiB
  float* accs = (float*)(ws + 2048 + 65536);              // 32 B
  int* done = (int*)(ws + 2048 + 65536 + 32);             // 4 B
  __hip_bfloat16* cb = (__hip_bfloat16*)(ws + 131072);    // 6 MiB
  float* logits = (float*)(ws + 131072 + 3ul * P_CLS * D_DIM * 2);

  size_t base = 131072 + 3ul * P_CLS * D_DIM * 2;
  size_t per_z = 3ul * P_CLS * P_CLS * 4;
  int KZ = (ws_size >= base + 4 * per_z) ? 4 : 2;

  hipLaunchKernelGGL(k_init, dim3(1), dim3(512), 0, stream, cnt, accs, done);
  hipLaunchKernelGGL(k_index, dim3((N + 255) / 256), dim3(256), 0, stream,
                     label, cnt, idx, N);
  hipLaunchKernelGGL(k_centers, dim3(P_CLS, 3), dim3(256), 0, stream,
                     fvp, fap, frp, cnt, idx, cb, accs);
  hipLaunchKernelGGL(k_gemm, dim3(64, 3, KZ), dim3(256), 0, stream, cb, logits);
  hipLaunchKernelGGL(k_lse, dim3(3 * P_CLS), dim3(256), 0, stream, logits, accs,
                     KZ, done, (float*)d_out, 1.0f / (float)N);
}